// Round 6
// baseline (189.105 us; speedup 1.0000x reference)
//
#include <hip/hip_runtime.h>
#include <hip/hip_bf16.h>

// Problem constants (fixed by setup_inputs)
#define B_SZ   32
#define I_CAPS 2048
#define J_CAPS 32
#define C_DIM  32
#define D_DIM  16

#define IT     8          // i's per LDS tile in routing kernel
#define TILES  8          // tiles per block -> 64 i per block
#define SPLIT  32         // i-splits (grid.x of routing kernel)
#define ROW_STRIDE 40     // padded f16 elems per (i,j) row in LDS (80 B, 16B-aligned)

typedef _Float16 f16x8 __attribute__((ext_vector_type(8)));
typedef _Float16 f16x4 __attribute__((ext_vector_type(4)));
typedef float    f32x4 __attribute__((ext_vector_type(4)));

__device__ __forceinline__ float h2f_lo(unsigned int p) {
    union { unsigned short s; _Float16 h; } cv; cv.s = (unsigned short)(p & 0xffffu);
    return (float)cv.h;
}
__device__ __forceinline__ float h2f_hi(unsigned int p) { return h2f_lo(p >> 16); }

// ---------------------------------------------------------------------------
// Kernel 1 (MFMA, software-pipelined, u stored as f16):
//   per i, u[:, i, m] = W_i[m(=j*32+c), d] @ x_i[d, b];  M=1024, N=32(b), K=16→32.
// grid = I_CAPS/2 blocks, 256 threads (4 waves); wave w owns m in [w*256,+256).
// i+1's 18 loads issue BEFORE i's compute; i's stores are younger in vmcnt
// order, so waits for i+1's operands never drain stores. D-frags bounce
// through a per-wave LDS transpose tile (wave-local lgkmcnt sync only);
// stores are 4x dwordx4 per group = full 64B lines.
// ---------------------------------------------------------------------------
#define MPAD 72   // f16 elems per b-row in transpose tile (144 B, 16B-aligned)
#define IPB  2

__device__ __forceinline__ void load_i(const float* __restrict__ W,
                                       const float* __restrict__ x,
                                       int i, int wave, int lm, int lq,
                                       float4 (&wv)[16], float4 (&xv)[2]) {
#pragma unroll
    for (int nt = 0; nt < 2; ++nt) {
        const int b = nt * 16 + lm;
        xv[nt] = *reinterpret_cast<const float4*>(
            &x[((size_t)b * I_CAPS + i) * D_DIM + lq * 4]);
    }
#pragma unroll
    for (int k = 0; k < 16; ++k) {
        const int mt = wave * 16 + k;
        const int j  = mt >> 1;
        const int c  = (mt & 1) * 16 + lm;
        wv[k] = *reinterpret_cast<const float4*>(
            &W[(((size_t)j * I_CAPS + i) * C_DIM + c) * D_DIM + lq * 4]);
    }
}

__device__ __forceinline__ void compute_i(int i, int wave, int lane, int lm, int lq,
                                          const float4 (&wv)[16], const float4 (&xv)[2],
                                          unsigned short* __restrict__ my,
                                          unsigned short* __restrict__ u) {
    // B fragments (upper K-half zeroed)
    f16x8 bfr[2];
#pragma unroll
    for (int nt = 0; nt < 2; ++nt) {
        f16x8 f = {};
        f[0] = (_Float16)xv[nt].x; f[1] = (_Float16)xv[nt].y;
        f[2] = (_Float16)xv[nt].z; f[3] = (_Float16)xv[nt].w;
        bfr[nt] = f;
    }

#pragma unroll
    for (int g = 0; g < 4; ++g) {          // 4 groups of 4 M-tiles
#pragma unroll
        for (int k4 = 0; k4 < 4; ++k4) {
            const int k = g * 4 + k4;
            f16x8 a = {};
            a[0] = (_Float16)wv[k].x; a[1] = (_Float16)wv[k].y;
            a[2] = (_Float16)wv[k].z; a[3] = (_Float16)wv[k].w;

            const f32x4 z = {0.f, 0.f, 0.f, 0.f};
            f32x4 d0 = __builtin_amdgcn_mfma_f32_16x16x32_f16(a, bfr[0], z, 0, 0, 0);
            f32x4 d1 = __builtin_amdgcn_mfma_f32_16x16x32_f16(a, bfr[1], z, 0, 0, 0);

            const int m_loc = k4 * 16 + lq * 4;
#pragma unroll
            for (int nt = 0; nt < 2; ++nt) {
                const f32x4 d = nt ? d1 : d0;
                f16x4 o;
                o[0] = (_Float16)d[0]; o[1] = (_Float16)d[1];
                o[2] = (_Float16)d[2]; o[3] = (_Float16)d[3];
                const int b = nt * 16 + lm;
                *reinterpret_cast<f16x4*>(&my[b * MPAD + m_loc]) = o;
            }
        }
        // wave-local cross-lane visibility of ds_writes
        asm volatile("s_waitcnt lgkmcnt(0)" ::: "memory");
        __builtin_amdgcn_sched_barrier(0);

        const int b_off = lane >> 3;         // 0..7
        const int m_off = (lane & 7) * 8;    // 8 m's = 16 B per lane
        const int m_base = wave * 256 + g * 64;
#pragma unroll
        for (int gb = 0; gb < 4; ++gb) {
            const int b = gb * 8 + b_off;
            const uint4 v = *reinterpret_cast<const uint4*>(&my[b * MPAD + m_off]);
            *reinterpret_cast<uint4*>(
                &u[((size_t)b * I_CAPS + i) * (J_CAPS * C_DIM) + m_base + m_off]) = v;
        }
        // DS ops complete in order per wave -> next group's ds_writes WAR-safe
    }
}

__global__ __launch_bounds__(256) void uhat_mfma(const float* __restrict__ W,
                                                 const float* __restrict__ x,
                                                 unsigned short* __restrict__ u) {
    const int t    = threadIdx.x;
    const int wave = t >> 6;
    const int lane = t & 63;
    const int lm   = lane & 15;
    const int lq   = lane >> 4;

    __shared__ unsigned short tr[4][32 * MPAD];   // 18 KiB
    unsigned short* my = tr[wave];

    const int i0 = blockIdx.x * IPB;

    float4 wvA[16], wvB[16], xvA[2], xvB[2];
    load_i(W, x, i0,     wave, lm, lq, wvA, xvA);   // oldest loads
    load_i(W, x, i0 + 1, wave, lm, lq, wvB, xvB);   // prefetch
    compute_i(i0,     wave, lane, lm, lq, wvA, xvA, my, u);
    compute_i(i0 + 1, wave, lane, lm, lq, wvB, xvB, my, u);
}

// ---------------------------------------------------------------------------
// Kernel 2: one routing pass; kernel BOUNDARY is the global barrier.
// Prologue (redundant per block, ~free): v_p = squash(s_prev[b]);
//   V = v_p (pass 1) or V1 + v_p (pass 2). Pass-1 isplit==0 blocks persist
//   v_1 -> V1 for pass 2. Pass 0: c uniform = 1/32, no V needed.
// Main: l = u[b,i,j,:].V[b,j,:]; c = softmax_j; s_out += c*u (atomic/block).
// grid = (SPLIT, B_SZ), 256 threads.
// ---------------------------------------------------------------------------
__global__ __launch_bounds__(256) void route_pass(const unsigned short* __restrict__ u,
                                                  const float* __restrict__ s_prev,
                                                  float* __restrict__ V1,
                                                  float* __restrict__ s_out,
                                                  int pass) {
    const int b      = blockIdx.y;
    const int isplit = blockIdx.x;
    const int i_base = isplit * (IT * TILES);
    const int t      = threadIdx.x;

    __shared__ unsigned short us[IT * J_CAPS * ROW_STRIDE]; // 20480 B
    __shared__ float Vs[J_CAPS * 33];                       // 4224 B
    __shared__ float cjs[IT * J_CAPS];                      // 1024 B

    const int jA = t & 31, iA = t >> 5;        // phase A: (i_loc, j)
    const int jB = t >> 3, c4 = (t & 7) * 4;   // phase B / prologue: (j, c-quad)

    // ---- prologue: redundant squash of s_prev -> Vs (uniform branch) ----
    if (pass > 0) {
        const size_t base = ((size_t)b * J_CAPS + jB) * C_DIM + c4;
        const float4 sv = *reinterpret_cast<const float4*>(&s_prev[base]);
        float sq = sv.x * sv.x + sv.y * sv.y + sv.z * sv.z + sv.w * sv.w;
#pragma unroll
        for (int msk = 4; msk >= 1; msk >>= 1) sq += __shfl_xor(sq, msk);
        const float scale = sq / ((1.f + sq) * (sqrtf(sq) + 1e-8f));
        float4 v;
        v.x = sv.x * scale; v.y = sv.y * scale;
        v.z = sv.z * scale; v.w = sv.w * scale;
        if (pass == 1 && isplit == 0)
            *reinterpret_cast<float4*>(&V1[base]) = v;   // persist v1 for pass 2
        if (pass == 2) {
            const float4 v1 = *reinterpret_cast<const float4*>(&V1[base]);
            v.x += v1.x; v.y += v1.y; v.z += v1.z; v.w += v1.w;
        }
        Vs[jB * 33 + c4 + 0] = v.x; Vs[jB * 33 + c4 + 1] = v.y;
        Vs[jB * 33 + c4 + 2] = v.z; Vs[jB * 33 + c4 + 3] = v.w;
    }

    float sacc0 = 0.f, sacc1 = 0.f, sacc2 = 0.f, sacc3 = 0.f;

    for (int tile = 0; tile < TILES; ++tile) {
        const int i0 = i_base + tile * IT;
        __syncthreads();   // prev phase B done; also guards Vs first use

        // stage u[b][i0..i0+IT) -> LDS (16 KiB, padded rows)
        {
            const uint4* gsrc = reinterpret_cast<const uint4*>(
                u + ((size_t)b * I_CAPS + i0) * J_CAPS * C_DIM);
#pragma unroll
            for (int k = 0; k < 4; ++k) {
                const int n  = t + k * 256;
                const int il = n >> 7, rem = n & 127, j = rem >> 2, q = rem & 3;
                *reinterpret_cast<uint4*>(
                    &us[(il * J_CAPS + j) * ROW_STRIDE + q * 8]) = gsrc[n];
            }
        }
        __syncthreads();

        // phase A: logits + softmax over j (32-lane groups); pass 0 -> 1/32
        if (pass == 0) {
            cjs[iA * J_CAPS + jA] = 1.0f / 32.0f;
        } else {
            const unsigned short* row = &us[(iA * J_CAPS + jA) * ROW_STRIDE];
            float l = 0.f;
#pragma unroll
            for (int cq = 0; cq < 8; ++cq) {
                const uint2 pk = *reinterpret_cast<const uint2*>(row + cq * 4);
                const float* Vr = &Vs[jA * 33 + cq * 4];
                l += h2f_lo(pk.x) * Vr[0] + h2f_hi(pk.x) * Vr[1]
                   + h2f_lo(pk.y) * Vr[2] + h2f_hi(pk.y) * Vr[3];
            }
            float m = l;
#pragma unroll
            for (int msk = 16; msk >= 1; msk >>= 1) m = fmaxf(m, __shfl_xor(m, msk));
            const float e = __expf(l - m);
            float ssum = e;
#pragma unroll
            for (int msk = 16; msk >= 1; msk >>= 1) ssum += __shfl_xor(ssum, msk);
            cjs[iA * J_CAPS + jA] = e / ssum;
        }
        __syncthreads();

        // phase B: s accumulation in registers
        {
#pragma unroll
            for (int il = 0; il < IT; ++il) {
                const float cj = cjs[il * J_CAPS + jB];
                const unsigned short* row = &us[(il * J_CAPS + jB) * ROW_STRIDE + c4];
                const uint2 pk = *reinterpret_cast<const uint2*>(row);
                sacc0 += cj * h2f_lo(pk.x);
                sacc1 += cj * h2f_hi(pk.x);
                sacc2 += cj * h2f_lo(pk.y);
                sacc3 += cj * h2f_hi(pk.y);
            }
        }
    }

    float* sp = &s_out[((size_t)b * J_CAPS + jB) * C_DIM + c4];
    atomicAdd(sp + 0, sacc0);
    atomicAdd(sp + 1, sacc1);
    atomicAdd(sp + 2, sacc2);
    atomicAdd(sp + 3, sacc3);
}

// ---------------------------------------------------------------------------
// Kernel 3: out = squash(s_final). grid = 128, 256 threads.
// ---------------------------------------------------------------------------
__global__ __launch_bounds__(256) void squash_out(const float* __restrict__ s,
                                                  float* __restrict__ out) {
    const int t   = threadIdx.x;
    const int row = blockIdx.x * 8 + (t >> 5);
    const int c   = t & 31;
    const float sv = s[row * 32 + c];
    float sq = sv * sv;
#pragma unroll
    for (int msk = 16; msk >= 1; msk >>= 1) sq += __shfl_xor(sq, msk);
    const float scale = sq / ((1.f + sq) * (sqrtf(sq) + 1e-8f));
    out[row * 32 + c] = sv * scale;
}

// ---------------------------------------------------------------------------
extern "C" void kernel_launch(void* const* d_in, const int* in_sizes, int n_in,
                              void* d_out, int out_size, void* d_ws, size_t ws_size,
                              hipStream_t stream) {
    const float* x = (const float*)d_in[0];
    const float* W = (const float*)d_in[1];
    // d_in[2] = routing_steps (device scalar) — fixed at 3 by setup_inputs.
    float* out = (float*)d_out;

    const size_t u_elems = (size_t)B_SZ * I_CAPS * J_CAPS * C_DIM;   // 64M f16
    const size_t sjc     = (size_t)B_SZ * J_CAPS * C_DIM;            // 32K floats

    unsigned short* u = (unsigned short*)d_ws;
    float* s0 = (float*)((char*)d_ws + u_elems * 2);
    float* s1 = s0 + sjc;
    float* s2 = s1 + sjc;
    float* V1 = s2 + sjc;

    // zero s0..s2, V1 (contiguous, 512 KiB)
    hipMemsetAsync(s0, 0, 4 * sjc * sizeof(float), stream);

    uhat_mfma<<<I_CAPS / IPB, 256, 0, stream>>>(W, x, u);

    route_pass<<<dim3(SPLIT, B_SZ), 256, 0, stream>>>(u, nullptr, V1, s0, 0);
    route_pass<<<dim3(SPLIT, B_SZ), 256, 0, stream>>>(u, s0, V1, s1, 1);
    route_pass<<<dim3(SPLIT, B_SZ), 256, 0, stream>>>(u, s1, V1, s2, 2);

    squash_out<<<(B_SZ * J_CAPS * C_DIM) / 256, 256, 0, stream>>>(s2, out);
}

// Round 9
// 165.321 us; speedup vs baseline: 1.1439x; 1.1439x over previous
//
#include <hip/hip_runtime.h>
#include <hip/hip_bf16.h>

// Problem constants (fixed by setup_inputs)
#define B_SZ   32
#define I_CAPS 2048
#define J_CAPS 32
#define C_DIM  32
#define D_DIM  16

#define IT     8          // i's per LDS tile in routing kernel
#define TILES  8          // tiles per block -> 64 i per block
#define SPLIT  32         // i-splits (grid.x of routing kernel)
#define ROW_STRIDE 40     // padded f16 elems per (i,j) row in LDS (80 B, 16B-aligned)
#define MPAD   72         // f16 elems per b-row in transpose tile (144 B, 16B-aligned)

typedef _Float16 f16x8 __attribute__((ext_vector_type(8)));
typedef _Float16 f16x4 __attribute__((ext_vector_type(4)));
typedef float    f32x4 __attribute__((ext_vector_type(4)));

__device__ __forceinline__ float h2f_lo(unsigned int p) {
    union { unsigned short s; _Float16 h; } cv; cv.s = (unsigned short)(p & 0xffffu);
    return (float)cv.h;
}
__device__ __forceinline__ float h2f_hi(unsigned int p) { return h2f_lo(p >> 16); }

// ---------------------------------------------------------------------------
// Kernel 1 (MFMA, round-4 structure + f16 u storage):
//   per i, u[:, i, m] = W_i[m(=j*32+c), d] @ x_i[d, b];  M=1024, N=32(b), K=16→32.
// grid = I_CAPS blocks, 256 threads (4 waves); wave w owns m in [w*256,+256).
// 16 W loads issued up front (compiler-scheduled); D-frags bounce through a
// per-wave LDS transpose tile (wave-local lgkmcnt sync only; DS ops complete
// in order per wave so tile reuse across groups is WAR-safe). Stores: 4x
// dwordx4 per group, each = 8 b's x 128 B contiguous = full 64B lines.
// ---------------------------------------------------------------------------
__global__ __launch_bounds__(256) void uhat_mfma(const float* __restrict__ W,
                                                 const float* __restrict__ x,
                                                 unsigned short* __restrict__ u) {
    const int t    = threadIdx.x;
    const int wave = t >> 6;
    const int lane = t & 63;
    const int lm   = lane & 15;   // A: c-low | B/D: b mod 16
    const int lq   = lane >> 4;   // d-quad  | D: m-quad

    __shared__ unsigned short tr[4][32 * MPAD];   // 18 KiB
    unsigned short* my = tr[wave];

    const int i = blockIdx.x;

    // B fragments from x (2 N-tiles of 16 b's); upper K-half zeroed.
    f16x8 bfr[2];
#pragma unroll
    for (int nt = 0; nt < 2; ++nt) {
        const int b = nt * 16 + lm;
        const float4 xv = *reinterpret_cast<const float4*>(
            &x[((size_t)b * I_CAPS + i) * D_DIM + lq * 4]);
        f16x8 f = {};
        f[0] = (_Float16)xv.x; f[1] = (_Float16)xv.y;
        f[2] = (_Float16)xv.z; f[3] = (_Float16)xv.w;
        bfr[nt] = f;
    }

    // Issue ALL 16 W loads for this i up front.
    float4 wv[16];
#pragma unroll
    for (int k = 0; k < 16; ++k) {
        const int mt = wave * 16 + k;              // M-tile id 0..63
        const int j  = mt >> 1;
        const int c  = (mt & 1) * 16 + lm;
        wv[k] = *reinterpret_cast<const float4*>(
            &W[(((size_t)j * I_CAPS + i) * C_DIM + c) * D_DIM + lq * 4]);
    }

#pragma unroll
    for (int g = 0; g < 4; ++g) {          // 4 groups of 4 M-tiles
#pragma unroll
        for (int k4 = 0; k4 < 4; ++k4) {
            const int k = g * 4 + k4;
            f16x8 a = {};
            a[0] = (_Float16)wv[k].x; a[1] = (_Float16)wv[k].y;
            a[2] = (_Float16)wv[k].z; a[3] = (_Float16)wv[k].w;

            const f32x4 z = {0.f, 0.f, 0.f, 0.f};
            f32x4 d0 = __builtin_amdgcn_mfma_f32_16x16x32_f16(a, bfr[0], z, 0, 0, 0);
            f32x4 d1 = __builtin_amdgcn_mfma_f32_16x16x32_f16(a, bfr[1], z, 0, 0, 0);

            // scatter into per-wave transpose tile: lane -> (b, m_loc)
            const int m_loc = k4 * 16 + lq * 4;
#pragma unroll
            for (int nt = 0; nt < 2; ++nt) {
                const f32x4 d = nt ? d1 : d0;
                f16x4 o;
                o[0] = (_Float16)d[0]; o[1] = (_Float16)d[1];
                o[2] = (_Float16)d[2]; o[3] = (_Float16)d[3];
                const int b = nt * 16 + lm;
                *reinterpret_cast<f16x4*>(&my[b * MPAD + m_loc]) = o;
            }
        }
        // Wave-local cross-lane visibility: drain this wave's ds_writes.
        asm volatile("s_waitcnt lgkmcnt(0)" ::: "memory");
        __builtin_amdgcn_sched_barrier(0);

        // coalesced store: each instr covers 8 b's x 128 B contiguous
        const int b_off = lane >> 3;         // 0..7
        const int m_off = (lane & 7) * 8;    // 8 m's = 16 B per lane
        const int m_base = wave * 256 + g * 64;
#pragma unroll
        for (int gb = 0; gb < 4; ++gb) {
            const int b = gb * 8 + b_off;
            const uint4 v = *reinterpret_cast<const uint4*>(&my[b * MPAD + m_off]);
            *reinterpret_cast<uint4*>(
                &u[((size_t)b * I_CAPS + i) * (J_CAPS * C_DIM) + m_base + m_off]) = v;
        }
        // next group's ds_writes are after these ds_reads in program order;
        // DS ops complete in order per wave -> no barrier needed.
    }
}

// ---------------------------------------------------------------------------
// Kernel 2: one routing pass; kernel BOUNDARY is the global barrier.
// Prologue (redundant per block, ~free): v_p = squash(s_prev[b]);
//   V = v_p (pass 1) or V1 + v_p (pass 2). Pass-1 isplit==0 blocks persist
//   v_1 -> V1 for pass 2. Pass 0: c uniform = 1/32, no V needed.
// Main loop uses T14 async-stage: tile t+1's 4 uint4 global loads are issued
// right after tile t's ds_write (ping-pong reg sets rA/rB, static indexing),
// so HBM latency hides under phases A+B instead of serializing per tile.
// grid = (SPLIT, B_SZ), 256 threads.
// ---------------------------------------------------------------------------
__global__ __launch_bounds__(256) void route_pass(const unsigned short* __restrict__ u,
                                                  const float* __restrict__ s_prev,
                                                  float* __restrict__ V1,
                                                  float* __restrict__ s_out,
                                                  int pass) {
    const int b      = blockIdx.y;
    const int isplit = blockIdx.x;
    const int i_base = isplit * (IT * TILES);
    const int t      = threadIdx.x;

    __shared__ unsigned short us[IT * J_CAPS * ROW_STRIDE]; // 20480 B
    __shared__ float Vs[J_CAPS * 33];                       // 4224 B
    __shared__ float cjs[IT * J_CAPS];                      // 1024 B

    const int jA = t & 31, iA = t >> 5;        // phase A: (i_loc, j)
    const int jB = t >> 3, c4 = (t & 7) * 4;   // phase B / prologue: (j, c-quad)

    // ---- prologue: redundant squash of s_prev -> Vs (uniform branch) ----
    if (pass > 0) {
        const size_t base = ((size_t)b * J_CAPS + jB) * C_DIM + c4;
        const float4 sv = *reinterpret_cast<const float4*>(&s_prev[base]);
        float sq = sv.x * sv.x + sv.y * sv.y + sv.z * sv.z + sv.w * sv.w;
#pragma unroll
        for (int msk = 4; msk >= 1; msk >>= 1) sq += __shfl_xor(sq, msk);
        const float scale = sq / ((1.f + sq) * (sqrtf(sq) + 1e-8f));
        float4 v;
        v.x = sv.x * scale; v.y = sv.y * scale;
        v.z = sv.z * scale; v.w = sv.w * scale;
        if (pass == 1 && isplit == 0)
            *reinterpret_cast<float4*>(&V1[base]) = v;   // persist v1 for pass 2
        if (pass == 2) {
            const float4 v1 = *reinterpret_cast<const float4*>(&V1[base]);
            v.x += v1.x; v.y += v1.y; v.z += v1.z; v.w += v1.w;
        }
        Vs[jB * 33 + c4 + 0] = v.x; Vs[jB * 33 + c4 + 1] = v.y;
        Vs[jB * 33 + c4 + 2] = v.z; Vs[jB * 33 + c4 + 3] = v.w;
    }

    float sacc0 = 0.f, sacc1 = 0.f, sacc2 = 0.f, sacc3 = 0.f;

    // tile source pointer (16 KiB per tile, fully coalesced uint4 reads)
    const uint4* gbase = reinterpret_cast<const uint4*>(
        u + ((size_t)b * I_CAPS + i_base) * (J_CAPS * C_DIM));
    // 1024 uint4 per tile (= IT*1024 f16)
#define TSRC(tile) (gbase + (size_t)(tile) * 1024)

    uint4 rA0, rA1, rA2, rA3, rB0, rB1, rB2, rB3;
    { const uint4* g = TSRC(0); rA0 = g[t]; rA1 = g[t+256]; rA2 = g[t+512]; rA3 = g[t+768]; }

    // ds_write of a staged reg set into padded LDS rows
#define STAGE_WRITE(R0, R1, R2, R3)                                             \
    {                                                                           \
        _Pragma("unroll")                                                       \
        for (int k = 0; k < 4; ++k) {                                           \
            const int n  = t + k * 256;                                         \
            const int il = n >> 7, rem = n & 127, j = rem >> 2, q = rem & 3;    \
            const uint4 rv = (k == 0) ? R0 : (k == 1) ? R1 : (k == 2) ? R2 : R3;\
            *reinterpret_cast<uint4*>(                                          \
                &us[(il * J_CAPS + j) * ROW_STRIDE + q * 8]) = rv;              \
        }                                                                       \
    }

#define PHASES(TILE_)                                                           \
    {                                                                           \
        __syncthreads();                                                        \
        if (pass == 0) {                                                        \
            cjs[iA * J_CAPS + jA] = 1.0f / 32.0f;                               \
        } else {                                                                \
            const unsigned short* row = &us[(iA * J_CAPS + jA) * ROW_STRIDE];   \
            float l = 0.f;                                                      \
            _Pragma("unroll")                                                   \
            for (int cq = 0; cq < 8; ++cq) {                                    \
                const uint2 pk = *reinterpret_cast<const uint2*>(row + cq * 4); \
                const float* Vr = &Vs[jA * 33 + cq * 4];                        \
                l += h2f_lo(pk.x) * Vr[0] + h2f_hi(pk.x) * Vr[1]                \
                   + h2f_lo(pk.y) * Vr[2] + h2f_hi(pk.y) * Vr[3];               \
            }                                                                   \
            float m = l;                                                        \
            _Pragma("unroll")                                                   \
            for (int msk = 16; msk >= 1; msk >>= 1) m = fmaxf(m, __shfl_xor(m, msk)); \
            const float e = __expf(l - m);                                      \
            float ssum = e;                                                     \
            _Pragma("unroll")                                                   \
            for (int msk = 16; msk >= 1; msk >>= 1) ssum += __shfl_xor(ssum, msk); \
            cjs[iA * J_CAPS + jA] = e / ssum;                                   \
        }                                                                       \
        __syncthreads();                                                        \
        _Pragma("unroll")                                                       \
        for (int il = 0; il < IT; ++il) {                                       \
            const float cj = cjs[il * J_CAPS + jB];                             \
            const unsigned short* row = &us[(il * J_CAPS + jB) * ROW_STRIDE + c4]; \
            const uint2 pk = *reinterpret_cast<const uint2*>(row);              \
            sacc0 += cj * h2f_lo(pk.x);                                         \
            sacc1 += cj * h2f_hi(pk.x);                                         \
            sacc2 += cj * h2f_lo(pk.y);                                         \
            sacc3 += cj * h2f_hi(pk.y);                                         \
        }                                                                       \
    }

#pragma unroll
    for (int tp = 0; tp < TILES / 2; ++tp) {
        // even tile: consume rA, prefetch odd tile into rB
        __syncthreads();                       // prev phase B done reading us
        STAGE_WRITE(rA0, rA1, rA2, rA3);
        { const uint4* g = TSRC(2 * tp + 1); rB0 = g[t]; rB1 = g[t+256]; rB2 = g[t+512]; rB3 = g[t+768]; }
        PHASES(2 * tp)

        // odd tile: consume rB, prefetch next even tile into rA
        __syncthreads();
        STAGE_WRITE(rB0, rB1, rB2, rB3);
        if (tp + 1 < TILES / 2) {
            const uint4* g = TSRC(2 * tp + 2); rA0 = g[t]; rA1 = g[t+256]; rA2 = g[t+512]; rA3 = g[t+768];
        }
        PHASES(2 * tp + 1)
    }
#undef TSRC
#undef STAGE_WRITE
#undef PHASES

    float* sp = &s_out[((size_t)b * J_CAPS + jB) * C_DIM + c4];
    atomicAdd(sp + 0, sacc0);
    atomicAdd(sp + 1, sacc1);
    atomicAdd(sp + 2, sacc2);
    atomicAdd(sp + 3, sacc3);
}

// ---------------------------------------------------------------------------
// Kernel 3: out = squash(s_final). grid = 128, 256 threads.
// ---------------------------------------------------------------------------
__global__ __launch_bounds__(256) void squash_out(const float* __restrict__ s,
                                                  float* __restrict__ out) {
    const int t   = threadIdx.x;
    const int row = blockIdx.x * 8 + (t >> 5);
    const int c   = t & 31;
    const float sv = s[row * 32 + c];
    float sq = sv * sv;
#pragma unroll
    for (int msk = 16; msk >= 1; msk >>= 1) sq += __shfl_xor(sq, msk);
    const float scale = sq / ((1.f + sq) * (sqrtf(sq) + 1e-8f));
    out[row * 32 + c] = sv * scale;
}

// ---------------------------------------------------------------------------
extern "C" void kernel_launch(void* const* d_in, const int* in_sizes, int n_in,
                              void* d_out, int out_size, void* d_ws, size_t ws_size,
                              hipStream_t stream) {
    const float* x = (const float*)d_in[0];
    const float* W = (const float*)d_in[1];
    // d_in[2] = routing_steps (device scalar) — fixed at 3 by setup_inputs.
    float* out = (float*)d_out;

    const size_t u_elems = (size_t)B_SZ * I_CAPS * J_CAPS * C_DIM;   // 64M f16
    const size_t sjc     = (size_t)B_SZ * J_CAPS * C_DIM;            // 32K floats

    unsigned short* u = (unsigned short*)d_ws;
    float* s0 = (float*)((char*)d_ws + u_elems * 2);
    float* s1 = s0 + sjc;
    float* s2 = s1 + sjc;
    float* V1 = s2 + sjc;

    // zero s0..s2, V1 (contiguous, 512 KiB)
    hipMemsetAsync(s0, 0, 4 * sjc * sizeof(float), stream);

    uhat_mfma<<<I_CAPS, 256, 0, stream>>>(W, x, u);

    route_pass<<<dim3(SPLIT, B_SZ), 256, 0, stream>>>(u, nullptr, V1, s0, 0);
    route_pass<<<dim3(SPLIT, B_SZ), 256, 0, stream>>>(u, s0, V1, s1, 1);
    route_pass<<<dim3(SPLIT, B_SZ), 256, 0, stream>>>(u, s1, V1, s2, 2);

    squash_out<<<(B_SZ * J_CAPS * C_DIM) / 256, 256, 0, stream>>>(s2, out);
}